// Round 9
// baseline (4258.696 us; speedup 1.0000x reference)
//
#include <hip/hip_runtime.h>
#include <math.h>

// B=1024, T=512, I=2, H=256, G=4H=1024
// LSTM: 64 blocks x 1024 threads (16 waves), 16 batch rows per block.
// Whole recurrent datapath in fp16 (W_hh and h), accumulate fp32 via
// mfma_f32_16x16x32_f16. Wave wv owns units [16wv,16wv+16) x all 4 gates ->
// each lane's D-fragment holds i,f,g,o preacts for its (row,unit) cells ->
// nonlinearity fully in registers. h double-buffered in swizzled LDS ->
// ONE barrier per step (phases of different waves overlap).
// W_hh pre-packed fragment-major; kt 0-1 cached in registers, kt 2-7 streamed
// from L2 each step via 2-deep rolling register buffer (constant addresses).

typedef _Float16 f16x8 __attribute__((ext_vector_type(8)));
typedef __attribute__((ext_vector_type(4))) float f32x4;

#define MFMA16F(a, b, c) __builtin_amdgcn_mfma_f32_16x16x32_f16((a), (b), (c), 0, 0, 0)

__device__ __forceinline__ float fsig(float x)  { return 1.f / (1.f + __expf(-x)); }
__device__ __forceinline__ float ftanh_(float x){ return 2.f / (1.f + __expf(-2.f * x)) - 1.f; }

// ---------------- W_hh fragment packing (fp16) ----------------
// wf element index = f*512 + lane*8, f = (wv*8 + kt)*4 + gt
// value[i] = fp16( W_hh[ gt*256 + wv*16 + (lane&15) ][ kt*32 + (lane>>4)*8 + i ] )
__global__ void pack_whh(const float* __restrict__ W, _Float16* __restrict__ wf)
{
    const int idx  = blockIdx.x * 256 + threadIdx.x;   // 0..32767
    const int lane = idx & 63;
    const int f    = idx >> 6;                          // 0..511
    const int gt   = f & 3;
    const int kt   = (f >> 2) & 7;
    const int wv   = f >> 5;
    const int g    = gt * 256 + wv * 16 + (lane & 15);
    const int k0   = kt * 32 + (lane >> 4) * 8;
    const float* src = W + (size_t)g * 256 + k0;
    f16x8 v;
#pragma unroll
    for (int i = 0; i < 8; ++i) v[i] = (_Float16)src[i];
    *(f16x8*)(wf + (size_t)idx * 8) = v;
}

// ---------------- transpose: out[c][r] = in[r][c] ----------------
__global__ void transpose_kernel(const float* __restrict__ in,
                                 float* __restrict__ out,
                                 int rows, int cols)
{
    __shared__ float tile[32][33];
    const int c0 = blockIdx.x * 32;
    const int r0 = blockIdx.y * 32;
    const int tx = threadIdx.x;
    const int ty = threadIdx.y;
#pragma unroll
    for (int i = 0; i < 4; ++i)
        tile[ty + i * 8][tx] = in[(r0 + ty + i * 8) * cols + (c0 + tx)];
    __syncthreads();
#pragma unroll
    for (int i = 0; i < 4; ++i)
        out[(c0 + ty + i * 8) * rows + (r0 + tx)] = tile[tx][ty + i * 8];
}

// ---------------- LSTM kernel ----------------
__global__ __launch_bounds__(1024)
void lstm_kernel(const float* __restrict__ x,        // [B][T][2]
                 const _Float16* __restrict__ wfrag, // packed fp16 W_hh frags
                 const float* __restrict__ W_ih,     // [1024][2]
                 const float* __restrict__ b_ih,     // [1024]
                 const float* __restrict__ b_hh,     // [1024]
                 float* __restrict__ hT)             // [B][256]
{
    // double-buffered h (fp16), XOR-swizzled. 2 x 16 rows x 256 units x 2B = 16 KB
    __shared__ __align__(16) _Float16 hbuf[2 * 16 * 256];

    const int tid  = threadIdx.x;
    const int lane = tid & 63;
    const int wv   = tid >> 6;        // wave 0..15
    const int fm   = lane & 15;
    const int fc   = lane >> 4;
    const int br   = blockIdx.x * 16; // batch row base
    const int u    = wv * 16 + fm;    // unit this lane owns in phase B

    // per-lane gate constants (gate order i,f,g,o along 4H)
    float bias[4], wi0[4], wi1[4];
#pragma unroll
    for (int gt = 0; gt < 4; ++gt) {
        const int g = gt * 256 + u;
        bias[gt] = b_ih[g] + b_hh[g];
        wi0[gt]  = W_ih[2 * g + 0];
        wi1[gt]  = W_ih[2 * g + 1];
    }

    for (int i = tid; i < 2 * 16 * 256; i += 1024) hbuf[i] = (_Float16)0.f;

    // this wave's fragment stream base
    const _Float16* wf_wave = wfrag + (size_t)wv * 16384 + lane * 8;

    // cache kt 0,1 (8 frags) in registers
    f16x8 wc[8];
#pragma unroll
    for (int q = 0; q < 8; ++q) wc[q] = *(const f16x8*)(wf_wave + q * 512);

    // A-read swizzled byte offsets within one h buffer
    int aoff[8];
#pragma unroll
    for (int kt = 0; kt < 8; ++kt)
        aoff[kt] = (fm * 512 + kt * 64 + fc * 16) ^ ((fm & 7) << 4);
    // h-write byte offsets (2B each), same swizzle
    int hoff[4];
#pragma unroll
    for (int r = 0; r < 4; ++r) {
        const int row = fc * 4 + r;
        hoff[r] = (row * 512 + u * 2) ^ ((row & 7) << 4);
    }

    const char* hb = (const char*)hbuf;
    const float* xrow = x + (size_t)br * 1024;

    // prime rolling W buffers: wb0 <- kt2, wb1 <- kt3
    f16x8 wb0[4], wb1[4];
#pragma unroll
    for (int gt = 0; gt < 4; ++gt) wb0[gt] = *(const f16x8*)(wf_wave + (8  + gt) * 512);
#pragma unroll
    for (int gt = 0; gt < 4; ++gt) wb1[gt] = *(const f16x8*)(wf_wave + (12 + gt) * 512);

    float c[4] = {0.f, 0.f, 0.f, 0.f};
    __syncthreads();

    for (int t = 0; t < 512; ++t) {
        const int cur = (t & 1) * 8192;       // byte offset of read buffer
        const int nxt = 8192 - cur;           // write buffer

        // x for this step (consumed in phase B)
        float xr0[4], xr1[4];
#pragma unroll
        for (int r = 0; r < 4; ++r) {
            const float2 xv = *(const float2*)(xrow + (size_t)(fc * 4 + r) * 1024 + 2 * t);
            xr0[r] = xv.x; xr1[r] = xv.y;
        }

        f32x4 acc[4];
#pragma unroll
        for (int gt = 0; gt < 4; ++gt) acc[gt] = (f32x4){0.f, 0.f, 0.f, 0.f};

        // kt 0,1 from register cache
#pragma unroll
        for (int kt = 0; kt < 2; ++kt) {
            const f16x8 a = *(const f16x8*)(hb + cur + aoff[kt]);
#pragma unroll
            for (int gt = 0; gt < 4; ++gt)
                acc[gt] = MFMA16F(a, wc[kt * 4 + gt], acc[gt]);
        }

        // kt 2..7 from rolling buffers; reload for kt+4 (wraps to next step's 2,3)
        {
            const f16x8 a2 = *(const f16x8*)(hb + cur + aoff[2]);
#pragma unroll
            for (int gt = 0; gt < 4; ++gt) acc[gt] = MFMA16F(a2, wb0[gt], acc[gt]);
#pragma unroll
            for (int gt = 0; gt < 4; ++gt) wb0[gt] = *(const f16x8*)(wf_wave + (16 + gt) * 512);

            const f16x8 a3 = *(const f16x8*)(hb + cur + aoff[3]);
#pragma unroll
            for (int gt = 0; gt < 4; ++gt) acc[gt] = MFMA16F(a3, wb1[gt], acc[gt]);
#pragma unroll
            for (int gt = 0; gt < 4; ++gt) wb1[gt] = *(const f16x8*)(wf_wave + (20 + gt) * 512);

            const f16x8 a4 = *(const f16x8*)(hb + cur + aoff[4]);
#pragma unroll
            for (int gt = 0; gt < 4; ++gt) acc[gt] = MFMA16F(a4, wb0[gt], acc[gt]);
#pragma unroll
            for (int gt = 0; gt < 4; ++gt) wb0[gt] = *(const f16x8*)(wf_wave + (24 + gt) * 512);

            const f16x8 a5 = *(const f16x8*)(hb + cur + aoff[5]);
#pragma unroll
            for (int gt = 0; gt < 4; ++gt) acc[gt] = MFMA16F(a5, wb1[gt], acc[gt]);
#pragma unroll
            for (int gt = 0; gt < 4; ++gt) wb1[gt] = *(const f16x8*)(wf_wave + (28 + gt) * 512);

            const f16x8 a6 = *(const f16x8*)(hb + cur + aoff[6]);
#pragma unroll
            for (int gt = 0; gt < 4; ++gt) acc[gt] = MFMA16F(a6, wb0[gt], acc[gt]);
#pragma unroll
            for (int gt = 0; gt < 4; ++gt) wb0[gt] = *(const f16x8*)(wf_wave + (8 + gt) * 512);

            const f16x8 a7 = *(const f16x8*)(hb + cur + aoff[7]);
#pragma unroll
            for (int gt = 0; gt < 4; ++gt) acc[gt] = MFMA16F(a7, wb1[gt], acc[gt]);
#pragma unroll
            for (int gt = 0; gt < 4; ++gt) wb1[gt] = *(const f16x8*)(wf_wave + (12 + gt) * 512);
        }

        // ---- phase B: in-register nonlinearity; D row = fc*4 + r, unit u ----
#pragma unroll
        for (int r = 0; r < 4; ++r) {
            const float si = acc[0][r] + fmaf(xr1[r], wi1[0], fmaf(xr0[r], wi0[0], bias[0]));
            const float sf = acc[1][r] + fmaf(xr1[r], wi1[1], fmaf(xr0[r], wi0[1], bias[1]));
            const float sg = acc[2][r] + fmaf(xr1[r], wi1[2], fmaf(xr0[r], wi0[2], bias[2]));
            const float so = acc[3][r] + fmaf(xr1[r], wi1[3], fmaf(xr0[r], wi0[3], bias[3]));
            const float gi = fsig(si);
            const float gf = fsig(sf);
            const float gg = ftanh_(sg);
            const float go = fsig(so);
            c[r] = gf * c[r] + gi * gg;
            const float h = go * ftanh_(c[r]);
            *(_Float16*)((char*)hbuf + nxt + hoff[r]) = (_Float16)h;
            if (t == 511) hT[(size_t)(br + fc * 4 + r) * 256 + u] = h;
        }
        __syncthreads();   // writes to buf[nxt] visible; everyone done with buf[cur]
    }
}

// ---------------- MLP head ----------------
__global__ void mlp_kernel(const float* __restrict__ hT,
                           const float* __restrict__ W1T,  // [256][256] W1T[k][j]
                           const float* __restrict__ b1,
                           const float* __restrict__ W2T,
                           const float* __restrict__ b2,
                           const float* __restrict__ W3,   // [256]
                           const float* __restrict__ b3,
                           float* __restrict__ out)        // [B]
{
    __shared__ float hs[8][256];
    __shared__ float a1[8][256];
    __shared__ float a2[8][256];
    __shared__ float p3[8][257];

    const int tid = threadIdx.x;
    const int br  = blockIdx.x * 8;

#pragma unroll
    for (int r = 0; r < 8; ++r) hs[r][tid] = hT[(size_t)(br + r) * 256 + tid];
    __syncthreads();

    {
        float acc[8];
#pragma unroll
        for (int r = 0; r < 8; ++r) acc[r] = b1[tid];
        for (int k = 0; k < 256; k += 4) {
            const float w0 = W1T[(k + 0) * 256 + tid];
            const float w1 = W1T[(k + 1) * 256 + tid];
            const float w2 = W1T[(k + 2) * 256 + tid];
            const float w3 = W1T[(k + 3) * 256 + tid];
#pragma unroll
            for (int r = 0; r < 8; ++r) {
                const float4 hv = *(const float4*)&hs[r][k];
                acc[r] = fmaf(w0, hv.x, acc[r]);
                acc[r] = fmaf(w1, hv.y, acc[r]);
                acc[r] = fmaf(w2, hv.z, acc[r]);
                acc[r] = fmaf(w3, hv.w, acc[r]);
            }
        }
#pragma unroll
        for (int r = 0; r < 8; ++r) a1[r][tid] = fmaxf(acc[r], 0.f);
    }
    __syncthreads();

    {
        float acc[8];
#pragma unroll
        for (int r = 0; r < 8; ++r) acc[r] = b2[tid];
        for (int k = 0; k < 256; k += 4) {
            const float w0 = W2T[(k + 0) * 256 + tid];
            const float w1 = W2T[(k + 1) * 256 + tid];
            const float w2 = W2T[(k + 2) * 256 + tid];
            const float w3 = W2T[(k + 3) * 256 + tid];
#pragma unroll
            for (int r = 0; r < 8; ++r) {
                const float4 hv = *(const float4*)&a1[r][k];
                acc[r] = fmaf(w0, hv.x, acc[r]);
                acc[r] = fmaf(w1, hv.y, acc[r]);
                acc[r] = fmaf(w2, hv.z, acc[r]);
                acc[r] = fmaf(w3, hv.w, acc[r]);
            }
        }
#pragma unroll
        for (int r = 0; r < 8; ++r) a2[r][tid] = fmaxf(acc[r], 0.f);
    }
    __syncthreads();

    {
        const float w = W3[tid];
#pragma unroll
        for (int r = 0; r < 8; ++r) p3[r][tid] = w * a2[r][tid];
    }
    __syncthreads();
    if (tid < 8) {
        float s = 0.f;
        for (int k = 0; k < 256; ++k) s += p3[tid][k];
        out[br + tid] = s + b3[0];
    }
}

// ---------------- launcher ----------------
extern "C" void kernel_launch(void* const* d_in, const int* in_sizes, int n_in,
                              void* d_out, int out_size, void* d_ws, size_t ws_size,
                              hipStream_t stream)
{
    const float* x    = (const float*)d_in[0];
    const float* W_ih = (const float*)d_in[1];
    const float* W_hh = (const float*)d_in[2];
    const float* b_ih = (const float*)d_in[3];
    const float* b_hh = (const float*)d_in[4];
    const float* W1   = (const float*)d_in[5];
    const float* b1   = (const float*)d_in[6];
    const float* W2   = (const float*)d_in[7];
    const float* b2   = (const float*)d_in[8];
    const float* W3   = (const float*)d_in[9];
    const float* b3   = (const float*)d_in[10];

    // workspace: hT 1MB | W1T 256KB | W2T 256KB | wfrag 512KB
    float*     hT    = (float*)d_ws;               // 1024*256
    float*     W1T   = hT + 1024 * 256;            // 256*256
    float*     W2T   = W1T + 256 * 256;            // 256*256
    _Float16*  wfrag = (_Float16*)(W2T + 256 * 256);  // 512*512 fp16

    pack_whh<<<128, 256, 0, stream>>>(W_hh, wfrag);
    transpose_kernel<<<dim3(8, 8), dim3(32, 8), 0, stream>>>(W1, W1T, 256, 256);
    transpose_kernel<<<dim3(8, 8), dim3(32, 8), 0, stream>>>(W2, W2T, 256, 256);

    lstm_kernel<<<64, 1024, 0, stream>>>(x, wfrag, W_ih, b_ih, b_hh, hT);
    mlp_kernel<<<128, 256, 0, stream>>>(hT, W1T, b1, W2T, b2, W3, b3, (float*)d_out);
}